// Round 15
// baseline (95.358 us; speedup 1.0000x reference)
//
#include <hip/hip_runtime.h>

// LoopEmbeddingNetwork, round 15.
// R14 post-mortem: attn plateaued at ~60us (co-limited); the persistent
// ~22us = prep + gap. prep is latency-bound: 392 blocks = 1.5 waves/SIMD,
// ~1550-FMA serial chain per thread, scalar weight loads unhidden.
// This round: 2 threads/node in prep (redundant h/x = 704 FMA, split qkv
// halves = 384 FMA each) -> chain 1088 FMA, waves x2. attn identical to R14.

typedef float f32x4 __attribute__((ext_vector_type(4)));
typedef __fp16 h2 __attribute__((ext_vector_type(2)));   // matches cvt_pkrtz return

static __device__ __forceinline__ unsigned h2u(h2 v) { return __builtin_bit_cast(unsigned, v); }
static __device__ __forceinline__ h2 u2h(unsigned v) { return __builtin_bit_cast(h2, v); }
static __device__ __forceinline__ h2 f2h(float v) { return __builtin_bit_cast(h2, v); }
static __device__ __forceinline__ float h2f(h2 v) { return __builtin_bit_cast(float, v); }
#define DPPH2(x, ctrl) u2h((unsigned)__builtin_amdgcn_update_dpp( \
    (int)h2u(x), (int)h2u(x), (ctrl), 0xF, 0xF, false))
#define SWZH(x, pat) u2h((unsigned)__builtin_amdgcn_ds_swizzle((int)h2u(x), (pat)))

#if defined(__has_builtin) && __has_builtin(__builtin_amdgcn_fdot2)
#define FDOT2(a, b, c) __builtin_amdgcn_fdot2((a), (b), (c), false)
#else
#define FDOT2(a, b, c) fmaf((float)(a).x, (float)(b).x, fmaf((float)(a).y, (float)(b).y, (c)))
#endif

#if defined(__has_builtin) && __has_builtin(__builtin_elementwise_fma)
#define PKFMA(a, b, c) __builtin_elementwise_fma((a), (b), (c))
#else
#define PKFMA(a, b, c) ((a) * (b) + (c))
#endif

// prep: 2 threads per node (halves of qkv); last block fuses out_proj+fc -> W3,
// packs fco weights, writes b3 (+ f32 fallback W3).
__global__ __launch_bounds__(256) void prep_kernel(
    const float* __restrict__ nf,
    const float* __restrict__ w1, const float* __restrict__ b1,
    const float* __restrict__ w2, const float* __restrict__ b2,
    const float* __restrict__ wip, const float* __restrict__ bip,
    const float* __restrict__ fcw, const float* __restrict__ fcb,
    const float* __restrict__ opw, const float* __restrict__ opb,
    const float* __restrict__ fow,
    float* __restrict__ qkvt, h2* __restrict__ w3h,
    h2* __restrict__ fowh, float* __restrict__ b3, float* __restrict__ w3f,
    int N)
{
    if ((int)blockIdx.x == (int)gridDim.x - 1) {
        __shared__ float lw[512];
        int t = threadIdx.x;
#pragma unroll
        for (int rep = 0; rep < 2; ++rep) {
            int id = t + rep * 256;
            int o = id >> 4, j = id & 15;
            float acc = 0.f;
#pragma unroll
            for (int e = 0; e < 16; ++e)
                acc = fmaf(fcw[o * 16 + e], opw[e * 16 + j], acc);
            lw[id] = acc;
        }
        if (t < 32) {
            float bb = fcb[t];
#pragma unroll
            for (int e = 0; e < 16; ++e) bb = fmaf(fcw[t * 16 + e], opb[e], bb);
            b3[t] = bb;
        }
        fowh[t]       = __builtin_amdgcn_cvt_pkrtz(fow[2 * t],       fow[2 * t + 1]);
        fowh[t + 256] = __builtin_amdgcn_cvt_pkrtz(fow[2 * t + 512], fow[2 * t + 513]);
        __syncthreads();
        w3h[t] = __builtin_amdgcn_cvt_pkrtz(lw[2 * t], lw[2 * t + 1]);
        w3f[t] = lw[t];
        w3f[t + 256] = lw[t + 256];
        return;
    }
    int gt = blockIdx.x * 256 + threadIdx.x;
    int n = gt >> 1;
    if (n >= N) return;
    int half = gt & 1;
    const float2* nfp = reinterpret_cast<const float2*>(nf);
    float2 p0 = nfp[n * 3 + 0], p1 = nfp[n * 3 + 1], p2 = nfp[n * 3 + 2];
    float f[6] = {p0.x, p0.y, p1.x, p1.y, p2.x, p2.y};
    float h[32];
#pragma unroll
    for (int o = 0; o < 32; ++o) {
        float acc = b1[o];
#pragma unroll
        for (int i = 0; i < 6; ++i) acc = fmaf(f[i], w1[o * 6 + i], acc);
        h[o] = fmaxf(acc, 0.f);
    }
    float x[16];
#pragma unroll
    for (int e = 0; e < 16; ++e) {
        float acc = b2[e];
#pragma unroll
        for (int i = 0; i < 32; ++i) acc = fmaf(h[i], w2[e * 32 + i], acc);
        x[e] = acc;
    }
    // this thread's half: qkv[half*24 .. half*24+23]
    int base = half * 24;
    float qkv[24];
#pragma unroll
    for (int c = 0; c < 24; ++c) {
        int cc = base + c;
        float acc = bip[cc];
#pragma unroll
        for (int e = 0; e < 16; ++e) acc = fmaf(x[e], wip[cc * 16 + e], acc);
        qkv[c] = acc;
    }
    const float cs = 0.35355339059327373f * 1.4426950408889634f; // 1/sqrt(8)*log2e
    if (half == 0) {
#pragma unroll
        for (int c = 0; c < 16; ++c) qkv[c] *= cs;   // q pre-scale (q = qkv[0..15])
    }
    h2 ph[12];
#pragma unroll
    for (int i = 0; i < 12; ++i)
        ph[i] = __builtin_amdgcn_cvt_pkrtz(qkv[2 * i], qkv[2 * i + 1]);
    f32x4* dst = reinterpret_cast<f32x4*>(qkvt) + (size_t)n * 6 + half * 3;
#pragma unroll
    for (int t2 = 0; t2 < 3; ++t2) {
        f32x4 w;
        w.x = h2f(ph[4 * t2 + 0]); w.y = h2f(ph[4 * t2 + 1]);
        w.z = h2f(ph[4 * t2 + 2]); w.w = h2f(ph[4 * t2 + 3]);
        dst[t2] = w;
    }
}

// 2 loops per thread: token l of loops 2g and 2g+1, phases interleaved.
__global__ __launch_bounds__(256) void attn_tail_kernel(
    const int* __restrict__ s2l, const float* __restrict__ qkvt,
    const h2* __restrict__ w3h, const float* __restrict__ b3,
    const h2* __restrict__ fowh, const float* __restrict__ fob,
    float* __restrict__ out, int B)
{
    int tid = blockIdx.x * 256 + threadIdx.x;
    int l = tid & 7;
    int g = tid >> 3;
    int npair = (B + 1) >> 1;
    if (g >= npair) return;
    int b0 = 2 * g, b1 = 2 * g + 1;
    bool have1 = (b1 < B);
    int idx0 = s2l[b0 * 8 + l];
    int idx1 = s2l[(have1 ? b1 : b0) * 8 + l];
    const f32x4* qp0 = reinterpret_cast<const f32x4*>(qkvt) + (size_t)idx0 * 6;
    const f32x4* qp1 = reinterpret_cast<const f32x4*>(qkvt) + (size_t)idx1 * 6;

    // all 6 dwordx4 per instance issued upfront: one visit per node line
    f32x4 x0 = qp0[0], x1 = qp0[1], x2 = qp0[2], x3 = qp0[3], x4 = qp0[4], x5 = qp0[5];
    f32x4 y0 = qp1[0], y1 = qp1[1], y2 = qp1[2], y3 = qp1[3], y4 = qp1[4], y5 = qp1[5];

    h2 qh[2][8], kh[2][8], vh[2][8];
    qh[0][0]=f2h(x0.x); qh[0][1]=f2h(x0.y); qh[0][2]=f2h(x0.z); qh[0][3]=f2h(x0.w);
    qh[0][4]=f2h(x1.x); qh[0][5]=f2h(x1.y); qh[0][6]=f2h(x1.z); qh[0][7]=f2h(x1.w);
    kh[0][0]=f2h(x2.x); kh[0][1]=f2h(x2.y); kh[0][2]=f2h(x2.z); kh[0][3]=f2h(x2.w);
    kh[0][4]=f2h(x3.x); kh[0][5]=f2h(x3.y); kh[0][6]=f2h(x3.z); kh[0][7]=f2h(x3.w);
    vh[0][0]=f2h(x4.x); vh[0][1]=f2h(x4.y); vh[0][2]=f2h(x4.z); vh[0][3]=f2h(x4.w);
    vh[0][4]=f2h(x5.x); vh[0][5]=f2h(x5.y); vh[0][6]=f2h(x5.z); vh[0][7]=f2h(x5.w);
    qh[1][0]=f2h(y0.x); qh[1][1]=f2h(y0.y); qh[1][2]=f2h(y0.z); qh[1][3]=f2h(y0.w);
    qh[1][4]=f2h(y1.x); qh[1][5]=f2h(y1.y); qh[1][6]=f2h(y1.z); qh[1][7]=f2h(y1.w);
    kh[1][0]=f2h(y2.x); kh[1][1]=f2h(y2.y); kh[1][2]=f2h(y2.z); kh[1][3]=f2h(y2.w);
    kh[1][4]=f2h(y3.x); kh[1][5]=f2h(y3.y); kh[1][6]=f2h(y3.z); kh[1][7]=f2h(y3.w);
    vh[1][0]=f2h(y4.x); vh[1][1]=f2h(y4.y); vh[1][2]=f2h(y4.z); vh[1][3]=f2h(y4.w);
    vh[1][4]=f2h(y5.x); vh[1][5]=f2h(y5.y); vh[1][6]=f2h(y5.z); vh[1][7]=f2h(y5.w);

    h2 k7[2][8];
#pragma unroll
    for (int d = 0; d < 8; ++d) {
        k7[0][d] = DPPH2(kh[0][d], 0x141);
        k7[1][d] = DPPH2(kh[1][d], 0x141);
    }

    float s0[2][8], s1[2][8];
#define SC_ID(i, slot, KS) { float u0 = 0.f, u1 = 0.f; \
    _Pragma("unroll") for (int d = 0; d < 4; ++d) { \
        u0 = FDOT2(qh[i][d], KS[i][d], u0); \
        u1 = FDOT2(qh[i][4 + d], KS[i][4 + d], u1); } \
    s0[i][slot] = u0; s1[i][slot] = u1; }
#define SC_DPP(i, slot, KS, CTRL) { float u0 = 0.f, u1 = 0.f; \
    _Pragma("unroll") for (int d = 0; d < 4; ++d) { \
        u0 = FDOT2(qh[i][d], DPPH2(KS[i][d], CTRL), u0); \
        u1 = FDOT2(qh[i][4 + d], DPPH2(KS[i][4 + d], CTRL), u1); } \
    s0[i][slot] = u0; s1[i][slot] = u1; }
    SC_ID(0, 0, kh)          SC_ID(1, 0, kh)
    SC_DPP(0, 1, kh, 0xB1)   SC_DPP(1, 1, kh, 0xB1)
    SC_DPP(0, 2, kh, 0x4E)   SC_DPP(1, 2, kh, 0x4E)
    SC_DPP(0, 3, kh, 0x1B)   SC_DPP(1, 3, kh, 0x1B)
    SC_DPP(0, 4, k7, 0x1B)   SC_DPP(1, 4, k7, 0x1B)
    SC_DPP(0, 5, k7, 0x4E)   SC_DPP(1, 5, k7, 0x4E)
    SC_DPP(0, 6, k7, 0xB1)   SC_DPP(1, 6, k7, 0xB1)
    SC_ID(0, 7, k7)          SC_ID(1, 7, k7)
#undef SC_ID
#undef SC_DPP

    // softmax, exp2 domain, no max-subtract (shift-invariant; |s| << 127);
    // normalized weights packed to h2 (both halves) for pk_fma combine.
    h2 eA[2][8], eB[2][8];
#pragma unroll
    for (int i = 0; i < 2; ++i) {
        float e0[8], e1[8];
        float sum0 = 0.f, sum1 = 0.f;
#pragma unroll
        for (int m = 0; m < 8; ++m) {
            e0[m] = exp2f(s0[i][m]); sum0 += e0[m];
            e1[m] = exp2f(s1[i][m]); sum1 += e1[m];
        }
        float r0 = __builtin_amdgcn_rcpf(sum0);
        float r1 = __builtin_amdgcn_rcpf(sum1);
#pragma unroll
        for (int m = 0; m < 8; ++m) {
            float n0 = e0[m] * r0, n1 = e1[m] * r1;
            eA[i][m] = __builtin_amdgcn_cvt_pkrtz(n0, n0);
            eB[i][m] = __builtin_amdgcn_cvt_pkrtz(n1, n1);
        }
    }

    h2 v7[2][8];
#pragma unroll
    for (int d = 0; d < 8; ++d) {
        v7[0][d] = DPPH2(vh[0][d], 0x141);
        v7[1][d] = DPPH2(vh[1][d], 0x141);
    }

    // ctx accumulated in packed fp16 (v_pk_fma_f16); cx[i][0..3]=head0 pairs,
    // cx[i][4..7]=head1 pairs -- directly the W3 input fragments.
    h2 cx[2][8];
    h2 hz; hz.x = (__fp16)0.f; hz.y = (__fp16)0.f;
#pragma unroll
    for (int i = 0; i < 2; ++i)
#pragma unroll
        for (int d = 0; d < 8; ++d) cx[i][d] = hz;
#define CTX_ID(i, slot, VS) { \
    _Pragma("unroll") for (int d = 0; d < 4; ++d) { \
        cx[i][d]     = PKFMA(eA[i][slot], VS[i][d],     cx[i][d]); \
        cx[i][4 + d] = PKFMA(eB[i][slot], VS[i][4 + d], cx[i][4 + d]); } }
#define CTX_DPP(i, slot, VS, CTRL) { \
    _Pragma("unroll") for (int d = 0; d < 4; ++d) { \
        cx[i][d]     = PKFMA(eA[i][slot], DPPH2(VS[i][d], CTRL),     cx[i][d]); \
        cx[i][4 + d] = PKFMA(eB[i][slot], DPPH2(VS[i][4 + d], CTRL), cx[i][4 + d]); } }
    CTX_ID(0, 0, vh)          CTX_ID(1, 0, vh)
    CTX_DPP(0, 1, vh, 0xB1)   CTX_DPP(1, 1, vh, 0xB1)
    CTX_DPP(0, 2, vh, 0x4E)   CTX_DPP(1, 2, vh, 0x4E)
    CTX_DPP(0, 3, vh, 0x1B)   CTX_DPP(1, 3, vh, 0x1B)
    CTX_DPP(0, 4, v7, 0x1B)   CTX_DPP(1, 4, v7, 0x1B)
    CTX_DPP(0, 5, v7, 0x4E)   CTX_DPP(1, 5, v7, 0x4E)
    CTX_DPP(0, 6, v7, 0xB1)   CTX_DPP(1, 6, v7, 0xB1)
    CTX_ID(0, 7, v7)          CTX_ID(1, 7, v7)
#undef CTX_ID
#undef CTX_DPP

    // fused out_proj+fc (16->32, relu) via fdot2; ctx already fp16 packed
    h2 yh[2][16];
#pragma unroll
    for (int i = 0; i < 16; ++i) {
        float ba = b3[2 * i], bb = b3[2 * i + 1];
        float ya0 = ba, yb0 = bb, ya1 = ba, yb1 = bb;
#pragma unroll
        for (int jj = 0; jj < 8; ++jj) {
            h2 wa = w3h[(2 * i) * 8 + jj];
            h2 wb = w3h[(2 * i + 1) * 8 + jj];
            ya0 = FDOT2(cx[0][jj], wa, ya0);
            ya1 = FDOT2(cx[1][jj], wa, ya1);
            yb0 = FDOT2(cx[0][jj], wb, yb0);
            yb1 = FDOT2(cx[1][jj], wb, yb1);
        }
        yh[0][i] = __builtin_amdgcn_cvt_pkrtz(fmaxf(ya0, 0.f), fmaxf(yb0, 0.f));
        yh[1][i] = __builtin_amdgcn_cvt_pkrtz(fmaxf(ya1, 0.f), fmaxf(yb1, 0.f));
    }

    // mean over 8 tokens: full ds_swizzle butterfly (xor1/xor2/xor4)
#pragma unroll
    for (int i = 0; i < 16; ++i) {
#pragma unroll
        for (int j = 0; j < 2; ++j) {
            yh[j][i] = yh[j][i] + SWZH(yh[j][i], 0x041F);
            yh[j][i] = yh[j][i] + SWZH(yh[j][i], 0x081F);
            yh[j][i] = yh[j][i] + SWZH(yh[j][i], 0x101F);
        }
    }

    // fco: weights loaded as 4 x dwordx4 per output row (L1-resident)
    const f32x4* fw4 = reinterpret_cast<const f32x4*>(fowh);
    float o4a[4], o4b[4];
#pragma unroll
    for (int j = 0; j < 4; ++j) {
        int oo = l * 4 + j;
        float acc0 = 0.f, acc1 = 0.f;
#pragma unroll
        for (int q = 0; q < 4; ++q) {
            f32x4 wv = fw4[oo * 4 + q];
            h2 w0 = f2h(wv.x), w1v = f2h(wv.y), w2v = f2h(wv.z), w3v = f2h(wv.w);
            acc0 = FDOT2(yh[0][q * 4 + 0], w0, acc0);
            acc1 = FDOT2(yh[1][q * 4 + 0], w0, acc1);
            acc0 = FDOT2(yh[0][q * 4 + 1], w1v, acc0);
            acc1 = FDOT2(yh[1][q * 4 + 1], w1v, acc1);
            acc0 = FDOT2(yh[0][q * 4 + 2], w2v, acc0);
            acc1 = FDOT2(yh[1][q * 4 + 2], w2v, acc1);
            acc0 = FDOT2(yh[0][q * 4 + 3], w3v, acc0);
            acc1 = FDOT2(yh[1][q * 4 + 3], w3v, acc1);
        }
        float bo = fob[oo];
        o4a[j] = fmaf(acc0, 0.125f, bo);
        o4b[j] = fmaf(acc1, 0.125f, bo);
    }
    f32x4 res0; res0.x = o4a[0]; res0.y = o4a[1]; res0.z = o4a[2]; res0.w = o4a[3];
    __builtin_nontemporal_store(res0, reinterpret_cast<f32x4*>(out) + (b0 * 8 + l));
    if (have1) {
        f32x4 res1; res1.x = o4b[0]; res1.y = o4b[1]; res1.z = o4b[2]; res1.w = o4b[3];
        __builtin_nontemporal_store(res1, reinterpret_cast<f32x4*>(out) + (b1 * 8 + l));
    }
}

// ---------------- fallback: monolithic kernel (if ws too small) ----------------
__global__ __launch_bounds__(256) void loop_embed_kernel(
    const float* __restrict__ nf, const int* __restrict__ s2l,
    const float* __restrict__ w1, const float* __restrict__ b1,
    const float* __restrict__ w2, const float* __restrict__ b2,
    const float* __restrict__ wip, const float* __restrict__ bip,
    const float* __restrict__ w3, const float* __restrict__ b3,
    const float* __restrict__ fow, const float* __restrict__ fob,
    float* __restrict__ out, int B)
{
    int tid = blockIdx.x * 256 + threadIdx.x;
    int b = tid >> 3;
    if (b >= B) return;
    int l = tid & 7;
    int idx = s2l[b * 8 + l];
    const float2* nfp = reinterpret_cast<const float2*>(nf);
    float2 p0 = nfp[idx * 3 + 0], p1 = nfp[idx * 3 + 1], p2 = nfp[idx * 3 + 2];
    float f[6] = {p0.x, p0.y, p1.x, p1.y, p2.x, p2.y};
    float h[32];
#pragma unroll
    for (int o = 0; o < 32; ++o) {
        float acc = b1[o];
#pragma unroll
        for (int i = 0; i < 6; ++i) acc = fmaf(f[i], w1[o * 6 + i], acc);
        h[o] = fmaxf(acc, 0.f);
    }
    float x[16];
#pragma unroll
    for (int e = 0; e < 16; ++e) {
        float acc = b2[e];
#pragma unroll
        for (int i = 0; i < 32; ++i) acc = fmaf(h[i], w2[e * 32 + i], acc);
        x[e] = acc;
    }
    float q[16], k[16], v[16];
#pragma unroll
    for (int c = 0; c < 16; ++c) {
        float aq = bip[c], ak = bip[16 + c], av = bip[32 + c];
#pragma unroll
        for (int e = 0; e < 16; ++e) {
            aq = fmaf(x[e], wip[c * 16 + e], aq);
            ak = fmaf(x[e], wip[(16 + c) * 16 + e], ak);
            av = fmaf(x[e], wip[(32 + c) * 16 + e], av);
        }
        q[c] = aq; k[c] = ak; v[c] = av;
    }
    int lane = threadIdx.x & 63;
    int gb = lane & 56;
    float s0[8], s1[8];
#pragma unroll
    for (int m = 0; m < 8; ++m) {
        float a0 = 0.f, a1 = 0.f;
#pragma unroll
        for (int d = 0; d < 8; ++d) {
            a0 = fmaf(q[d], __shfl(k[d], gb + m, 64), a0);
            a1 = fmaf(q[8 + d], __shfl(k[8 + d], gb + m, 64), a1);
        }
        s0[m] = a0; s1[m] = a1;
    }
    const float sc = 0.35355339059327373f;
    float mx0 = s0[0], mx1 = s1[0];
#pragma unroll
    for (int m = 1; m < 8; ++m) { mx0 = fmaxf(mx0, s0[m]); mx1 = fmaxf(mx1, s1[m]); }
    float e0[8], e1[8];
    float sum0 = 0.f, sum1 = 0.f;
#pragma unroll
    for (int m = 0; m < 8; ++m) {
        e0[m] = __expf((s0[m] - mx0) * sc); sum0 += e0[m];
        e1[m] = __expf((s1[m] - mx1) * sc); sum1 += e1[m];
    }
    float r0 = 1.0f / sum0, r1 = 1.0f / sum1;
    float ctx[16];
#pragma unroll
    for (int c = 0; c < 16; ++c) ctx[c] = 0.f;
#pragma unroll
    for (int m = 0; m < 8; ++m) {
#pragma unroll
        for (int c = 0; c < 8; ++c)
            ctx[c] = fmaf(e0[m], __shfl(v[c], gb + m, 64), ctx[c]);
#pragma unroll
        for (int c = 8; c < 16; ++c)
            ctx[c] = fmaf(e1[m], __shfl(v[c], gb + m, 64), ctx[c]);
    }
#pragma unroll
    for (int c = 0; c < 8; ++c)  ctx[c] *= r0;
#pragma unroll
    for (int c = 8; c < 16; ++c) ctx[c] *= r1;
    float y[32];
#pragma unroll
    for (int o = 0; o < 32; ++o) {
        float acc = b3[o];
#pragma unroll
        for (int j = 0; j < 16; ++j) acc = fmaf(ctx[j], w3[o * 16 + j], acc);
        y[o] = fmaxf(acc, 0.f);
    }
#pragma unroll
    for (int o = 0; o < 32; ++o) {
        y[o] += __shfl_xor(y[o], 1, 64);
        y[o] += __shfl_xor(y[o], 2, 64);
        y[o] += __shfl_xor(y[o], 4, 64);
    }
    float o4[4];
#pragma unroll
    for (int j = 0; j < 4; ++j) {
        int oo = l * 4 + j;
        float acc = 0.f;
#pragma unroll
        for (int i = 0; i < 32; ++i) acc = fmaf(y[i], fow[oo * 32 + i], acc);
        o4[j] = fmaf(acc, 0.125f, fob[oo]);
    }
    reinterpret_cast<float4*>(out)[b * 8 + l] = make_float4(o4[0], o4[1], o4[2], o4[3]);
}

extern "C" void kernel_launch(void* const* d_in, const int* in_sizes, int n_in,
                              void* d_out, int out_size, void* d_ws, size_t ws_size,
                              hipStream_t stream) {
    const float* nf  = (const float*)d_in[0];
    const int*   s2l = (const int*)d_in[1];
    const float* w1  = (const float*)d_in[2];
    const float* b1  = (const float*)d_in[3];
    const float* w2  = (const float*)d_in[4];
    const float* b2  = (const float*)d_in[5];
    const float* wip = (const float*)d_in[6];
    const float* bip = (const float*)d_in[7];
    const float* opw = (const float*)d_in[8];
    const float* opb = (const float*)d_in[9];
    const float* fcw = (const float*)d_in[10];
    const float* fcb = (const float*)d_in[11];
    const float* fow = (const float*)d_in[12];
    const float* fob = (const float*)d_in[13];
    float* out = (float*)d_out;

    int N = in_sizes[0] / 6;
    int B = in_sizes[1] / 8;

    // ws layout (dwords): [0,256) w3h  [256,768) fowh  [768,800) b3
    //                     [800,1312) w3f (fallback)  [1312,...) fp16 qkv table
    unsigned* wsd = (unsigned*)d_ws;
    h2*    w3h  = (h2*)(wsd);
    h2*    fowh = (h2*)(wsd + 256);
    float* b3   = (float*)(wsd + 768);
    float* w3f  = (float*)(wsd + 800);
    float* qkvt = (float*)(wsd + 1312);   // 16B-aligned (1312*4 = 5248)

    size_t need = (size_t)(1312 + (size_t)N * 12) * 4;   // 12 dwords = 96 B/node

    if (ws_size >= need) {
        int NB = (2 * N + 255) / 256;     // 2 threads per node
        prep_kernel<<<NB + 1, 256, 0, stream>>>(
            nf, w1, b1, w2, b2, wip, bip, fcw, fcb, opw, opb, fow,
            qkvt, w3h, fowh, b3, w3f, N);
        int npair = (B + 1) >> 1;
        int blocks = (npair * 8 + 255) / 256;
        attn_tail_kernel<<<blocks, 256, 0, stream>>>(
            s2l, qkvt, w3h, b3, fowh, fob, out, B);
    } else {
        prep_kernel<<<1, 256, 0, stream>>>(
            nf, w1, b1, w2, b2, wip, bip, fcw, fcb, opw, opb, fow,
            qkvt, w3h, fowh, b3, w3f, 0);
        int blocks = (B * 8 + 255) / 256;
        loop_embed_kernel<<<blocks, 256, 0, stream>>>(
            nf, s2l, w1, b1, w2, b2, wip, bip, w3f, b3, fow, fob, out, B);
    }
    (void)n_in; (void)out_size;
}

// Round 16
// 82.437 us; speedup vs baseline: 1.1567x; 1.1567x over previous
//
#include <hip/hip_runtime.h>

// LoopEmbeddingNetwork, round 16 = round 14 restore (best known: 82.4us).
// R15 post-mortem: 2-threads/node prep regressed 13us (prep is issue-bound,
// not latency-bound; redundant h/x work + doubled s_load streams lost).
// Structure: prep (1 thr/node, fp16 qkv table 96B/node, q pre-scaled by
// 1/sqrt(8)*log2e; last block fuses out_proj+fc->W3 + packs fco) then
// attn_tail (2 loops/thread ILP, DPP XOR-slot attention, pk_fma fp16 ctx,
// fdot2 W3/fco, ds_swizzle mean butterfly, nontemporal stores).

typedef float f32x4 __attribute__((ext_vector_type(4)));
typedef __fp16 h2 __attribute__((ext_vector_type(2)));   // matches cvt_pkrtz return

static __device__ __forceinline__ unsigned h2u(h2 v) { return __builtin_bit_cast(unsigned, v); }
static __device__ __forceinline__ h2 u2h(unsigned v) { return __builtin_bit_cast(h2, v); }
static __device__ __forceinline__ h2 f2h(float v) { return __builtin_bit_cast(h2, v); }
static __device__ __forceinline__ float h2f(h2 v) { return __builtin_bit_cast(float, v); }
#define DPPH2(x, ctrl) u2h((unsigned)__builtin_amdgcn_update_dpp( \
    (int)h2u(x), (int)h2u(x), (ctrl), 0xF, 0xF, false))
#define SWZH(x, pat) u2h((unsigned)__builtin_amdgcn_ds_swizzle((int)h2u(x), (pat)))

#if defined(__has_builtin) && __has_builtin(__builtin_amdgcn_fdot2)
#define FDOT2(a, b, c) __builtin_amdgcn_fdot2((a), (b), (c), false)
#else
#define FDOT2(a, b, c) fmaf((float)(a).x, (float)(b).x, fmaf((float)(a).y, (float)(b).y, (c)))
#endif

#if defined(__has_builtin) && __has_builtin(__builtin_elementwise_fma)
#define PKFMA(a, b, c) __builtin_elementwise_fma((a), (b), (c))
#else
#define PKFMA(a, b, c) ((a) * (b) + (c))
#endif

// prep: blocks [0, NB) compute per-node qkv (fp16, 96 B/node, q pre-scaled);
// last block fuses out_proj+fc -> W3 (fp16-packed + f32 fallback), packs fco
// weights, writes b3.
__global__ __launch_bounds__(256) void prep_kernel(
    const float* __restrict__ nf,
    const float* __restrict__ w1, const float* __restrict__ b1,
    const float* __restrict__ w2, const float* __restrict__ b2,
    const float* __restrict__ wip, const float* __restrict__ bip,
    const float* __restrict__ fcw, const float* __restrict__ fcb,
    const float* __restrict__ opw, const float* __restrict__ opb,
    const float* __restrict__ fow,
    float* __restrict__ qkvt, h2* __restrict__ w3h,
    h2* __restrict__ fowh, float* __restrict__ b3, float* __restrict__ w3f,
    int N)
{
    if ((int)blockIdx.x == (int)gridDim.x - 1) {
        __shared__ float lw[512];
        int t = threadIdx.x;
#pragma unroll
        for (int rep = 0; rep < 2; ++rep) {
            int id = t + rep * 256;
            int o = id >> 4, j = id & 15;
            float acc = 0.f;
#pragma unroll
            for (int e = 0; e < 16; ++e)
                acc = fmaf(fcw[o * 16 + e], opw[e * 16 + j], acc);
            lw[id] = acc;
        }
        if (t < 32) {
            float bb = fcb[t];
#pragma unroll
            for (int e = 0; e < 16; ++e) bb = fmaf(fcw[t * 16 + e], opb[e], bb);
            b3[t] = bb;
        }
        fowh[t]       = __builtin_amdgcn_cvt_pkrtz(fow[2 * t],       fow[2 * t + 1]);
        fowh[t + 256] = __builtin_amdgcn_cvt_pkrtz(fow[2 * t + 512], fow[2 * t + 513]);
        __syncthreads();
        w3h[t] = __builtin_amdgcn_cvt_pkrtz(lw[2 * t], lw[2 * t + 1]);
        w3f[t] = lw[t];
        w3f[t + 256] = lw[t + 256];
        return;
    }
    int n = blockIdx.x * 256 + threadIdx.x;
    if (n >= N) return;
    const float2* nfp = reinterpret_cast<const float2*>(nf);
    float2 p0 = nfp[n * 3 + 0], p1 = nfp[n * 3 + 1], p2 = nfp[n * 3 + 2];
    float f[6] = {p0.x, p0.y, p1.x, p1.y, p2.x, p2.y};
    float h[32];
#pragma unroll
    for (int o = 0; o < 32; ++o) {
        float acc = b1[o];
#pragma unroll
        for (int i = 0; i < 6; ++i) acc = fmaf(f[i], w1[o * 6 + i], acc);
        h[o] = fmaxf(acc, 0.f);
    }
    float x[16];
#pragma unroll
    for (int e = 0; e < 16; ++e) {
        float acc = b2[e];
#pragma unroll
        for (int i = 0; i < 32; ++i) acc = fmaf(h[i], w2[e * 32 + i], acc);
        x[e] = acc;
    }
    float qkv[48];
#pragma unroll
    for (int c = 0; c < 48; ++c) {
        float acc = bip[c];
#pragma unroll
        for (int e = 0; e < 16; ++e) acc = fmaf(x[e], wip[c * 16 + e], acc);
        qkv[c] = acc;
    }
    const float cs = 0.35355339059327373f * 1.4426950408889634f; // 1/sqrt(8)*log2e
#pragma unroll
    for (int c = 0; c < 16; ++c) qkv[c] *= cs;
    h2 ph[24];
#pragma unroll
    for (int i = 0; i < 24; ++i)
        ph[i] = __builtin_amdgcn_cvt_pkrtz(qkv[2 * i], qkv[2 * i + 1]);
    f32x4* dst = reinterpret_cast<f32x4*>(qkvt) + (size_t)n * 6;
#pragma unroll
    for (int t2 = 0; t2 < 6; ++t2) {
        f32x4 w;
        w.x = h2f(ph[4 * t2 + 0]); w.y = h2f(ph[4 * t2 + 1]);
        w.z = h2f(ph[4 * t2 + 2]); w.w = h2f(ph[4 * t2 + 3]);
        dst[t2] = w;
    }
}

// 2 loops per thread: token l of loops 2g and 2g+1, phases interleaved.
__global__ __launch_bounds__(256) void attn_tail_kernel(
    const int* __restrict__ s2l, const float* __restrict__ qkvt,
    const h2* __restrict__ w3h, const float* __restrict__ b3,
    const h2* __restrict__ fowh, const float* __restrict__ fob,
    float* __restrict__ out, int B)
{
    int tid = blockIdx.x * 256 + threadIdx.x;
    int l = tid & 7;
    int g = tid >> 3;
    int npair = (B + 1) >> 1;
    if (g >= npair) return;
    int b0 = 2 * g, b1 = 2 * g + 1;
    bool have1 = (b1 < B);
    int idx0 = s2l[b0 * 8 + l];
    int idx1 = s2l[(have1 ? b1 : b0) * 8 + l];
    const f32x4* qp0 = reinterpret_cast<const f32x4*>(qkvt) + (size_t)idx0 * 6;
    const f32x4* qp1 = reinterpret_cast<const f32x4*>(qkvt) + (size_t)idx1 * 6;

    // all 6 dwordx4 per instance issued upfront: one visit per node line
    f32x4 x0 = qp0[0], x1 = qp0[1], x2 = qp0[2], x3 = qp0[3], x4 = qp0[4], x5 = qp0[5];
    f32x4 y0 = qp1[0], y1 = qp1[1], y2 = qp1[2], y3 = qp1[3], y4 = qp1[4], y5 = qp1[5];

    h2 qh[2][8], kh[2][8], vh[2][8];
    qh[0][0]=f2h(x0.x); qh[0][1]=f2h(x0.y); qh[0][2]=f2h(x0.z); qh[0][3]=f2h(x0.w);
    qh[0][4]=f2h(x1.x); qh[0][5]=f2h(x1.y); qh[0][6]=f2h(x1.z); qh[0][7]=f2h(x1.w);
    kh[0][0]=f2h(x2.x); kh[0][1]=f2h(x2.y); kh[0][2]=f2h(x2.z); kh[0][3]=f2h(x2.w);
    kh[0][4]=f2h(x3.x); kh[0][5]=f2h(x3.y); kh[0][6]=f2h(x3.z); kh[0][7]=f2h(x3.w);
    vh[0][0]=f2h(x4.x); vh[0][1]=f2h(x4.y); vh[0][2]=f2h(x4.z); vh[0][3]=f2h(x4.w);
    vh[0][4]=f2h(x5.x); vh[0][5]=f2h(x5.y); vh[0][6]=f2h(x5.z); vh[0][7]=f2h(x5.w);
    qh[1][0]=f2h(y0.x); qh[1][1]=f2h(y0.y); qh[1][2]=f2h(y0.z); qh[1][3]=f2h(y0.w);
    qh[1][4]=f2h(y1.x); qh[1][5]=f2h(y1.y); qh[1][6]=f2h(y1.z); qh[1][7]=f2h(y1.w);
    kh[1][0]=f2h(y2.x); kh[1][1]=f2h(y2.y); kh[1][2]=f2h(y2.z); kh[1][3]=f2h(y2.w);
    kh[1][4]=f2h(y3.x); kh[1][5]=f2h(y3.y); kh[1][6]=f2h(y3.z); kh[1][7]=f2h(y3.w);
    vh[1][0]=f2h(y4.x); vh[1][1]=f2h(y4.y); vh[1][2]=f2h(y4.z); vh[1][3]=f2h(y4.w);
    vh[1][4]=f2h(y5.x); vh[1][5]=f2h(y5.y); vh[1][6]=f2h(y5.z); vh[1][7]=f2h(y5.w);

    h2 k7[2][8];
#pragma unroll
    for (int d = 0; d < 8; ++d) {
        k7[0][d] = DPPH2(kh[0][d], 0x141);
        k7[1][d] = DPPH2(kh[1][d], 0x141);
    }

    float s0[2][8], s1[2][8];
#define SC_ID(i, slot, KS) { float u0 = 0.f, u1 = 0.f; \
    _Pragma("unroll") for (int d = 0; d < 4; ++d) { \
        u0 = FDOT2(qh[i][d], KS[i][d], u0); \
        u1 = FDOT2(qh[i][4 + d], KS[i][4 + d], u1); } \
    s0[i][slot] = u0; s1[i][slot] = u1; }
#define SC_DPP(i, slot, KS, CTRL) { float u0 = 0.f, u1 = 0.f; \
    _Pragma("unroll") for (int d = 0; d < 4; ++d) { \
        u0 = FDOT2(qh[i][d], DPPH2(KS[i][d], CTRL), u0); \
        u1 = FDOT2(qh[i][4 + d], DPPH2(KS[i][4 + d], CTRL), u1); } \
    s0[i][slot] = u0; s1[i][slot] = u1; }
    SC_ID(0, 0, kh)          SC_ID(1, 0, kh)
    SC_DPP(0, 1, kh, 0xB1)   SC_DPP(1, 1, kh, 0xB1)
    SC_DPP(0, 2, kh, 0x4E)   SC_DPP(1, 2, kh, 0x4E)
    SC_DPP(0, 3, kh, 0x1B)   SC_DPP(1, 3, kh, 0x1B)
    SC_DPP(0, 4, k7, 0x1B)   SC_DPP(1, 4, k7, 0x1B)
    SC_DPP(0, 5, k7, 0x4E)   SC_DPP(1, 5, k7, 0x4E)
    SC_DPP(0, 6, k7, 0xB1)   SC_DPP(1, 6, k7, 0xB1)
    SC_ID(0, 7, k7)          SC_ID(1, 7, k7)
#undef SC_ID
#undef SC_DPP

    // softmax, exp2 domain, no max-subtract (shift-invariant; |s| << 127);
    // normalized weights packed to h2 (both halves) for pk_fma combine.
    h2 eA[2][8], eB[2][8];
#pragma unroll
    for (int i = 0; i < 2; ++i) {
        float e0[8], e1[8];
        float sum0 = 0.f, sum1 = 0.f;
#pragma unroll
        for (int m = 0; m < 8; ++m) {
            e0[m] = exp2f(s0[i][m]); sum0 += e0[m];
            e1[m] = exp2f(s1[i][m]); sum1 += e1[m];
        }
        float r0 = __builtin_amdgcn_rcpf(sum0);
        float r1 = __builtin_amdgcn_rcpf(sum1);
#pragma unroll
        for (int m = 0; m < 8; ++m) {
            float n0 = e0[m] * r0, n1 = e1[m] * r1;
            eA[i][m] = __builtin_amdgcn_cvt_pkrtz(n0, n0);
            eB[i][m] = __builtin_amdgcn_cvt_pkrtz(n1, n1);
        }
    }

    h2 v7[2][8];
#pragma unroll
    for (int d = 0; d < 8; ++d) {
        v7[0][d] = DPPH2(vh[0][d], 0x141);
        v7[1][d] = DPPH2(vh[1][d], 0x141);
    }

    // ctx accumulated in packed fp16 (v_pk_fma_f16); cx[i][0..3]=head0 pairs,
    // cx[i][4..7]=head1 pairs -- directly the W3 input fragments.
    h2 cx[2][8];
    h2 hz; hz.x = (__fp16)0.f; hz.y = (__fp16)0.f;
#pragma unroll
    for (int i = 0; i < 2; ++i)
#pragma unroll
        for (int d = 0; d < 8; ++d) cx[i][d] = hz;
#define CTX_ID(i, slot, VS) { \
    _Pragma("unroll") for (int d = 0; d < 4; ++d) { \
        cx[i][d]     = PKFMA(eA[i][slot], VS[i][d],     cx[i][d]); \
        cx[i][4 + d] = PKFMA(eB[i][slot], VS[i][4 + d], cx[i][4 + d]); } }
#define CTX_DPP(i, slot, VS, CTRL) { \
    _Pragma("unroll") for (int d = 0; d < 4; ++d) { \
        cx[i][d]     = PKFMA(eA[i][slot], DPPH2(VS[i][d], CTRL),     cx[i][d]); \
        cx[i][4 + d] = PKFMA(eB[i][slot], DPPH2(VS[i][4 + d], CTRL), cx[i][4 + d]); } }
    CTX_ID(0, 0, vh)          CTX_ID(1, 0, vh)
    CTX_DPP(0, 1, vh, 0xB1)   CTX_DPP(1, 1, vh, 0xB1)
    CTX_DPP(0, 2, vh, 0x4E)   CTX_DPP(1, 2, vh, 0x4E)
    CTX_DPP(0, 3, vh, 0x1B)   CTX_DPP(1, 3, vh, 0x1B)
    CTX_DPP(0, 4, v7, 0x1B)   CTX_DPP(1, 4, v7, 0x1B)
    CTX_DPP(0, 5, v7, 0x4E)   CTX_DPP(1, 5, v7, 0x4E)
    CTX_DPP(0, 6, v7, 0xB1)   CTX_DPP(1, 6, v7, 0xB1)
    CTX_ID(0, 7, v7)          CTX_ID(1, 7, v7)
#undef CTX_ID
#undef CTX_DPP

    // fused out_proj+fc (16->32, relu) via fdot2; ctx already fp16 packed
    h2 yh[2][16];
#pragma unroll
    for (int i = 0; i < 16; ++i) {
        float ba = b3[2 * i], bb = b3[2 * i + 1];
        float ya0 = ba, yb0 = bb, ya1 = ba, yb1 = bb;
#pragma unroll
        for (int jj = 0; jj < 8; ++jj) {
            h2 wa = w3h[(2 * i) * 8 + jj];
            h2 wb = w3h[(2 * i + 1) * 8 + jj];
            ya0 = FDOT2(cx[0][jj], wa, ya0);
            ya1 = FDOT2(cx[1][jj], wa, ya1);
            yb0 = FDOT2(cx[0][jj], wb, yb0);
            yb1 = FDOT2(cx[1][jj], wb, yb1);
        }
        yh[0][i] = __builtin_amdgcn_cvt_pkrtz(fmaxf(ya0, 0.f), fmaxf(yb0, 0.f));
        yh[1][i] = __builtin_amdgcn_cvt_pkrtz(fmaxf(ya1, 0.f), fmaxf(yb1, 0.f));
    }

    // mean over 8 tokens: full ds_swizzle butterfly (xor1/xor2/xor4)
#pragma unroll
    for (int i = 0; i < 16; ++i) {
#pragma unroll
        for (int j = 0; j < 2; ++j) {
            yh[j][i] = yh[j][i] + SWZH(yh[j][i], 0x041F);
            yh[j][i] = yh[j][i] + SWZH(yh[j][i], 0x081F);
            yh[j][i] = yh[j][i] + SWZH(yh[j][i], 0x101F);
        }
    }

    // fco: weights loaded as 4 x dwordx4 per output row (L1-resident)
    const f32x4* fw4 = reinterpret_cast<const f32x4*>(fowh);
    float o4a[4], o4b[4];
#pragma unroll
    for (int j = 0; j < 4; ++j) {
        int oo = l * 4 + j;
        float acc0 = 0.f, acc1 = 0.f;
#pragma unroll
        for (int q = 0; q < 4; ++q) {
            f32x4 wv = fw4[oo * 4 + q];
            h2 w0 = f2h(wv.x), w1v = f2h(wv.y), w2v = f2h(wv.z), w3v = f2h(wv.w);
            acc0 = FDOT2(yh[0][q * 4 + 0], w0, acc0);
            acc1 = FDOT2(yh[1][q * 4 + 0], w0, acc1);
            acc0 = FDOT2(yh[0][q * 4 + 1], w1v, acc0);
            acc1 = FDOT2(yh[1][q * 4 + 1], w1v, acc1);
            acc0 = FDOT2(yh[0][q * 4 + 2], w2v, acc0);
            acc1 = FDOT2(yh[1][q * 4 + 2], w2v, acc1);
            acc0 = FDOT2(yh[0][q * 4 + 3], w3v, acc0);
            acc1 = FDOT2(yh[1][q * 4 + 3], w3v, acc1);
        }
        float bo = fob[oo];
        o4a[j] = fmaf(acc0, 0.125f, bo);
        o4b[j] = fmaf(acc1, 0.125f, bo);
    }
    f32x4 res0; res0.x = o4a[0]; res0.y = o4a[1]; res0.z = o4a[2]; res0.w = o4a[3];
    __builtin_nontemporal_store(res0, reinterpret_cast<f32x4*>(out) + (b0 * 8 + l));
    if (have1) {
        f32x4 res1; res1.x = o4b[0]; res1.y = o4b[1]; res1.z = o4b[2]; res1.w = o4b[3];
        __builtin_nontemporal_store(res1, reinterpret_cast<f32x4*>(out) + (b1 * 8 + l));
    }
}

// ---------------- fallback: monolithic kernel (if ws too small) ----------------
__global__ __launch_bounds__(256) void loop_embed_kernel(
    const float* __restrict__ nf, const int* __restrict__ s2l,
    const float* __restrict__ w1, const float* __restrict__ b1,
    const float* __restrict__ w2, const float* __restrict__ b2,
    const float* __restrict__ wip, const float* __restrict__ bip,
    const float* __restrict__ w3, const float* __restrict__ b3,
    const float* __restrict__ fow, const float* __restrict__ fob,
    float* __restrict__ out, int B)
{
    int tid = blockIdx.x * 256 + threadIdx.x;
    int b = tid >> 3;
    if (b >= B) return;
    int l = tid & 7;
    int idx = s2l[b * 8 + l];
    const float2* nfp = reinterpret_cast<const float2*>(nf);
    float2 p0 = nfp[idx * 3 + 0], p1 = nfp[idx * 3 + 1], p2 = nfp[idx * 3 + 2];
    float f[6] = {p0.x, p0.y, p1.x, p1.y, p2.x, p2.y};
    float h[32];
#pragma unroll
    for (int o = 0; o < 32; ++o) {
        float acc = b1[o];
#pragma unroll
        for (int i = 0; i < 6; ++i) acc = fmaf(f[i], w1[o * 6 + i], acc);
        h[o] = fmaxf(acc, 0.f);
    }
    float x[16];
#pragma unroll
    for (int e = 0; e < 16; ++e) {
        float acc = b2[e];
#pragma unroll
        for (int i = 0; i < 32; ++i) acc = fmaf(h[i], w2[e * 32 + i], acc);
        x[e] = acc;
    }
    float q[16], k[16], v[16];
#pragma unroll
    for (int c = 0; c < 16; ++c) {
        float aq = bip[c], ak = bip[16 + c], av = bip[32 + c];
#pragma unroll
        for (int e = 0; e < 16; ++e) {
            aq = fmaf(x[e], wip[c * 16 + e], aq);
            ak = fmaf(x[e], wip[(16 + c) * 16 + e], ak);
            av = fmaf(x[e], wip[(32 + c) * 16 + e], av);
        }
        q[c] = aq; k[c] = ak; v[c] = av;
    }
    int lane = threadIdx.x & 63;
    int gb = lane & 56;
    float s0[8], s1[8];
#pragma unroll
    for (int m = 0; m < 8; ++m) {
        float a0 = 0.f, a1 = 0.f;
#pragma unroll
        for (int d = 0; d < 8; ++d) {
            a0 = fmaf(q[d], __shfl(k[d], gb + m, 64), a0);
            a1 = fmaf(q[8 + d], __shfl(k[8 + d], gb + m, 64), a1);
        }
        s0[m] = a0; s1[m] = a1;
    }
    const float sc = 0.35355339059327373f;
    float mx0 = s0[0], mx1 = s1[0];
#pragma unroll
    for (int m = 1; m < 8; ++m) { mx0 = fmaxf(mx0, s0[m]); mx1 = fmaxf(mx1, s1[m]); }
    float e0[8], e1[8];
    float sum0 = 0.f, sum1 = 0.f;
#pragma unroll
    for (int m = 0; m < 8; ++m) {
        e0[m] = __expf((s0[m] - mx0) * sc); sum0 += e0[m];
        e1[m] = __expf((s1[m] - mx1) * sc); sum1 += e1[m];
    }
    float r0 = 1.0f / sum0, r1 = 1.0f / sum1;
    float ctx[16];
#pragma unroll
    for (int c = 0; c < 16; ++c) ctx[c] = 0.f;
#pragma unroll
    for (int m = 0; m < 8; ++m) {
#pragma unroll
        for (int c = 0; c < 8; ++c)
            ctx[c] = fmaf(e0[m], __shfl(v[c], gb + m, 64), ctx[c]);
#pragma unroll
        for (int c = 8; c < 16; ++c)
            ctx[c] = fmaf(e1[m], __shfl(v[c], gb + m, 64), ctx[c]);
    }
#pragma unroll
    for (int c = 0; c < 8; ++c)  ctx[c] *= r0;
#pragma unroll
    for (int c = 8; c < 16; ++c) ctx[c] *= r1;
    float y[32];
#pragma unroll
    for (int o = 0; o < 32; ++o) {
        float acc = b3[o];
#pragma unroll
        for (int j = 0; j < 16; ++j) acc = fmaf(ctx[j], w3[o * 16 + j], acc);
        y[o] = fmaxf(acc, 0.f);
    }
#pragma unroll
    for (int o = 0; o < 32; ++o) {
        y[o] += __shfl_xor(y[o], 1, 64);
        y[o] += __shfl_xor(y[o], 2, 64);
        y[o] += __shfl_xor(y[o], 4, 64);
    }
    float o4[4];
#pragma unroll
    for (int j = 0; j < 4; ++j) {
        int oo = l * 4 + j;
        float acc = 0.f;
#pragma unroll
        for (int i = 0; i < 32; ++i) acc = fmaf(y[i], fow[oo * 32 + i], acc);
        o4[j] = fmaf(acc, 0.125f, fob[oo]);
    }
    reinterpret_cast<float4*>(out)[b * 8 + l] = make_float4(o4[0], o4[1], o4[2], o4[3]);
}

extern "C" void kernel_launch(void* const* d_in, const int* in_sizes, int n_in,
                              void* d_out, int out_size, void* d_ws, size_t ws_size,
                              hipStream_t stream) {
    const float* nf  = (const float*)d_in[0];
    const int*   s2l = (const int*)d_in[1];
    const float* w1  = (const float*)d_in[2];
    const float* b1  = (const float*)d_in[3];
    const float* w2  = (const float*)d_in[4];
    const float* b2  = (const float*)d_in[5];
    const float* wip = (const float*)d_in[6];
    const float* bip = (const float*)d_in[7];
    const float* opw = (const float*)d_in[8];
    const float* opb = (const float*)d_in[9];
    const float* fcw = (const float*)d_in[10];
    const float* fcb = (const float*)d_in[11];
    const float* fow = (const float*)d_in[12];
    const float* fob = (const float*)d_in[13];
    float* out = (float*)d_out;

    int N = in_sizes[0] / 6;
    int B = in_sizes[1] / 8;

    // ws layout (dwords): [0,256) w3h  [256,768) fowh  [768,800) b3
    //                     [800,1312) w3f (fallback)  [1312,...) fp16 qkv table
    unsigned* wsd = (unsigned*)d_ws;
    h2*    w3h  = (h2*)(wsd);
    h2*    fowh = (h2*)(wsd + 256);
    float* b3   = (float*)(wsd + 768);
    float* w3f  = (float*)(wsd + 800);
    float* qkvt = (float*)(wsd + 1312);   // 16B-aligned (1312*4 = 5248)

    size_t need = (size_t)(1312 + (size_t)N * 12) * 4;   // 12 dwords = 96 B/node

    if (ws_size >= need) {
        int NB = (N + 255) / 256;
        prep_kernel<<<NB + 1, 256, 0, stream>>>(
            nf, w1, b1, w2, b2, wip, bip, fcw, fcb, opw, opb, fow,
            qkvt, w3h, fowh, b3, w3f, N);
        int npair = (B + 1) >> 1;
        int blocks = (npair * 8 + 255) / 256;
        attn_tail_kernel<<<blocks, 256, 0, stream>>>(
            s2l, qkvt, w3h, b3, fowh, fob, out, B);
    } else {
        prep_kernel<<<1, 256, 0, stream>>>(
            nf, w1, b1, w2, b2, wip, bip, fcw, fcb, opw, opb, fow,
            qkvt, w3h, fowh, b3, w3f, 0);
        int blocks = (B * 8 + 255) / 256;
        loop_embed_kernel<<<blocks, 256, 0, stream>>>(
            nf, s2l, w1, b1, w2, b2, wip, bip, w3f, b3, fow, fob, out, B);
    }
    (void)n_in; (void)out_size;
}

// Round 17
// 75.976 us; speedup vs baseline: 1.2551x; 1.0850x over previous
//
#include <hip/hip_runtime.h>

// LoopEmbeddingNetwork, round 17.
// R16 confirmed best-known 82.4us (attn 60 + prep/gap 22). prep is
// issue-bound (R15 evidence). This round halves prep's per-thread work
// without changing parallelism: per-block fp16 weight staging in TYPED h2
// LDS (no punning), fc2+in_proj via fdot2 (VALU 1550->~900), weight reads
// moved to the idle DS pipe as uniform broadcasts. attn identical to R16.

typedef float f32x4 __attribute__((ext_vector_type(4)));
typedef __fp16 h2 __attribute__((ext_vector_type(2)));   // matches cvt_pkrtz return

static __device__ __forceinline__ unsigned h2u(h2 v) { return __builtin_bit_cast(unsigned, v); }
static __device__ __forceinline__ h2 u2h(unsigned v) { return __builtin_bit_cast(h2, v); }
static __device__ __forceinline__ h2 f2h(float v) { return __builtin_bit_cast(h2, v); }
static __device__ __forceinline__ float h2f(h2 v) { return __builtin_bit_cast(float, v); }
#define DPPH2(x, ctrl) u2h((unsigned)__builtin_amdgcn_update_dpp( \
    (int)h2u(x), (int)h2u(x), (ctrl), 0xF, 0xF, false))
#define SWZH(x, pat) u2h((unsigned)__builtin_amdgcn_ds_swizzle((int)h2u(x), (pat)))

#if defined(__has_builtin) && __has_builtin(__builtin_amdgcn_fdot2)
#define FDOT2(a, b, c) __builtin_amdgcn_fdot2((a), (b), (c), false)
#else
#define FDOT2(a, b, c) fmaf((float)(a).x, (float)(b).x, fmaf((float)(a).y, (float)(b).y, (c)))
#endif

#if defined(__has_builtin) && __has_builtin(__builtin_elementwise_fma)
#define PKFMA(a, b, c) __builtin_elementwise_fma((a), (b), (c))
#else
#define PKFMA(a, b, c) ((a) * (b) + (c))
#endif

// prep: blocks [0, NB) compute per-node qkv (fp16, 96 B/node, q pre-scaled);
// last block fuses out_proj+fc -> W3 (fp16-packed + f32 fallback), packs fco
// weights, writes b3. Node blocks stage fp16 w2/wip in LDS and use fdot2.
__global__ __launch_bounds__(256) void prep_kernel(
    const float* __restrict__ nf,
    const float* __restrict__ w1, const float* __restrict__ b1,
    const float* __restrict__ w2, const float* __restrict__ b2,
    const float* __restrict__ wip, const float* __restrict__ bip,
    const float* __restrict__ fcw, const float* __restrict__ fcb,
    const float* __restrict__ opw, const float* __restrict__ opb,
    const float* __restrict__ fow,
    float* __restrict__ qkvt, h2* __restrict__ w3h,
    h2* __restrict__ fowh, float* __restrict__ b3, float* __restrict__ w3f,
    int N)
{
    if ((int)blockIdx.x == (int)gridDim.x - 1) {
        __shared__ float lw[512];
        int t = threadIdx.x;
#pragma unroll
        for (int rep = 0; rep < 2; ++rep) {
            int id = t + rep * 256;
            int o = id >> 4, j = id & 15;
            float acc = 0.f;
#pragma unroll
            for (int e = 0; e < 16; ++e)
                acc = fmaf(fcw[o * 16 + e], opw[e * 16 + j], acc);
            lw[id] = acc;
        }
        if (t < 32) {
            float bb = fcb[t];
#pragma unroll
            for (int e = 0; e < 16; ++e) bb = fmaf(fcw[t * 16 + e], opb[e], bb);
            b3[t] = bb;
        }
        fowh[t]       = __builtin_amdgcn_cvt_pkrtz(fow[2 * t],       fow[2 * t + 1]);
        fowh[t + 256] = __builtin_amdgcn_cvt_pkrtz(fow[2 * t + 512], fow[2 * t + 513]);
        __syncthreads();
        w3h[t] = __builtin_amdgcn_cvt_pkrtz(lw[2 * t], lw[2 * t + 1]);
        w3f[t] = lw[t];
        w3f[t + 256] = lw[t + 256];
        return;
    }

    // stage fp16-packed fc2/in_proj weights in LDS (typed h2 -- no punning).
    // w2h[e*16+j] = (w2[e*32+2j], w2[e*32+2j+1]); wiph[c*8+p] = (wip[c*16+2p], ...).
    __shared__ h2 w2h[256];
    __shared__ h2 wiph[384];
    int t = threadIdx.x;
    w2h[t] = __builtin_amdgcn_cvt_pkrtz(w2[2 * t], w2[2 * t + 1]);
    wiph[t] = __builtin_amdgcn_cvt_pkrtz(wip[2 * t], wip[2 * t + 1]);
    if (t < 128)
        wiph[256 + t] = __builtin_amdgcn_cvt_pkrtz(wip[512 + 2 * t], wip[513 + 2 * t]);
    __syncthreads();

    int n = blockIdx.x * 256 + t;
    if (n >= N) return;
    const float2* nfp = reinterpret_cast<const float2*>(nf);
    float2 p0 = nfp[n * 3 + 0], p1 = nfp[n * 3 + 1], p2 = nfp[n * 3 + 2];
    float f[6] = {p0.x, p0.y, p1.x, p1.y, p2.x, p2.y};
    float h[32];
#pragma unroll
    for (int o = 0; o < 32; ++o) {
        float acc = b1[o];
#pragma unroll
        for (int i = 0; i < 6; ++i) acc = fmaf(f[i], w1[o * 6 + i], acc);
        h[o] = fmaxf(acc, 0.f);
    }
    // pack h -> fp16 pairs; fc2 via fdot2 from LDS weights
    h2 hh[16];
#pragma unroll
    for (int i = 0; i < 16; ++i)
        hh[i] = __builtin_amdgcn_cvt_pkrtz(h[2 * i], h[2 * i + 1]);
    float x[16];
#pragma unroll
    for (int e = 0; e < 16; ++e) {
        float acc = b2[e];
#pragma unroll
        for (int i = 0; i < 16; ++i) acc = FDOT2(hh[i], w2h[e * 16 + i], acc);
        x[e] = acc;
    }
    // pack x -> fp16 pairs; in_proj via fdot2 from LDS weights
    h2 xh[8];
#pragma unroll
    for (int i = 0; i < 8; ++i)
        xh[i] = __builtin_amdgcn_cvt_pkrtz(x[2 * i], x[2 * i + 1]);
    float qkv[48];
#pragma unroll
    for (int c = 0; c < 48; ++c) {
        float acc = bip[c];
#pragma unroll
        for (int i = 0; i < 8; ++i) acc = FDOT2(xh[i], wiph[c * 8 + i], acc);
        qkv[c] = acc;
    }
    const float cs = 0.35355339059327373f * 1.4426950408889634f; // 1/sqrt(8)*log2e
#pragma unroll
    for (int c = 0; c < 16; ++c) qkv[c] *= cs;
    h2 ph[24];
#pragma unroll
    for (int i = 0; i < 24; ++i)
        ph[i] = __builtin_amdgcn_cvt_pkrtz(qkv[2 * i], qkv[2 * i + 1]);
    f32x4* dst = reinterpret_cast<f32x4*>(qkvt) + (size_t)n * 6;
#pragma unroll
    for (int t2 = 0; t2 < 6; ++t2) {
        f32x4 w;
        w.x = h2f(ph[4 * t2 + 0]); w.y = h2f(ph[4 * t2 + 1]);
        w.z = h2f(ph[4 * t2 + 2]); w.w = h2f(ph[4 * t2 + 3]);
        dst[t2] = w;
    }
}

// 2 loops per thread: token l of loops 2g and 2g+1, phases interleaved.
__global__ __launch_bounds__(256) void attn_tail_kernel(
    const int* __restrict__ s2l, const float* __restrict__ qkvt,
    const h2* __restrict__ w3h, const float* __restrict__ b3,
    const h2* __restrict__ fowh, const float* __restrict__ fob,
    float* __restrict__ out, int B)
{
    int tid = blockIdx.x * 256 + threadIdx.x;
    int l = tid & 7;
    int g = tid >> 3;
    int npair = (B + 1) >> 1;
    if (g >= npair) return;
    int b0 = 2 * g, b1 = 2 * g + 1;
    bool have1 = (b1 < B);
    int idx0 = s2l[b0 * 8 + l];
    int idx1 = s2l[(have1 ? b1 : b0) * 8 + l];
    const f32x4* qp0 = reinterpret_cast<const f32x4*>(qkvt) + (size_t)idx0 * 6;
    const f32x4* qp1 = reinterpret_cast<const f32x4*>(qkvt) + (size_t)idx1 * 6;

    // all 6 dwordx4 per instance issued upfront: one visit per node line
    f32x4 x0 = qp0[0], x1 = qp0[1], x2 = qp0[2], x3 = qp0[3], x4 = qp0[4], x5 = qp0[5];
    f32x4 y0 = qp1[0], y1 = qp1[1], y2 = qp1[2], y3 = qp1[3], y4 = qp1[4], y5 = qp1[5];

    h2 qh[2][8], kh[2][8], vh[2][8];
    qh[0][0]=f2h(x0.x); qh[0][1]=f2h(x0.y); qh[0][2]=f2h(x0.z); qh[0][3]=f2h(x0.w);
    qh[0][4]=f2h(x1.x); qh[0][5]=f2h(x1.y); qh[0][6]=f2h(x1.z); qh[0][7]=f2h(x1.w);
    kh[0][0]=f2h(x2.x); kh[0][1]=f2h(x2.y); kh[0][2]=f2h(x2.z); kh[0][3]=f2h(x2.w);
    kh[0][4]=f2h(x3.x); kh[0][5]=f2h(x3.y); kh[0][6]=f2h(x3.z); kh[0][7]=f2h(x3.w);
    vh[0][0]=f2h(x4.x); vh[0][1]=f2h(x4.y); vh[0][2]=f2h(x4.z); vh[0][3]=f2h(x4.w);
    vh[0][4]=f2h(x5.x); vh[0][5]=f2h(x5.y); vh[0][6]=f2h(x5.z); vh[0][7]=f2h(x5.w);
    qh[1][0]=f2h(y0.x); qh[1][1]=f2h(y0.y); qh[1][2]=f2h(y0.z); qh[1][3]=f2h(y0.w);
    qh[1][4]=f2h(y1.x); qh[1][5]=f2h(y1.y); qh[1][6]=f2h(y1.z); qh[1][7]=f2h(y1.w);
    kh[1][0]=f2h(y2.x); kh[1][1]=f2h(y2.y); kh[1][2]=f2h(y2.z); kh[1][3]=f2h(y2.w);
    kh[1][4]=f2h(y3.x); kh[1][5]=f2h(y3.y); kh[1][6]=f2h(y3.z); kh[1][7]=f2h(y3.w);
    vh[1][0]=f2h(y4.x); vh[1][1]=f2h(y4.y); vh[1][2]=f2h(y4.z); vh[1][3]=f2h(y4.w);
    vh[1][4]=f2h(y5.x); vh[1][5]=f2h(y5.y); vh[1][6]=f2h(y5.z); vh[1][7]=f2h(y5.w);

    h2 k7[2][8];
#pragma unroll
    for (int d = 0; d < 8; ++d) {
        k7[0][d] = DPPH2(kh[0][d], 0x141);
        k7[1][d] = DPPH2(kh[1][d], 0x141);
    }

    float s0[2][8], s1[2][8];
#define SC_ID(i, slot, KS) { float u0 = 0.f, u1 = 0.f; \
    _Pragma("unroll") for (int d = 0; d < 4; ++d) { \
        u0 = FDOT2(qh[i][d], KS[i][d], u0); \
        u1 = FDOT2(qh[i][4 + d], KS[i][4 + d], u1); } \
    s0[i][slot] = u0; s1[i][slot] = u1; }
#define SC_DPP(i, slot, KS, CTRL) { float u0 = 0.f, u1 = 0.f; \
    _Pragma("unroll") for (int d = 0; d < 4; ++d) { \
        u0 = FDOT2(qh[i][d], DPPH2(KS[i][d], CTRL), u0); \
        u1 = FDOT2(qh[i][4 + d], DPPH2(KS[i][4 + d], CTRL), u1); } \
    s0[i][slot] = u0; s1[i][slot] = u1; }
    SC_ID(0, 0, kh)          SC_ID(1, 0, kh)
    SC_DPP(0, 1, kh, 0xB1)   SC_DPP(1, 1, kh, 0xB1)
    SC_DPP(0, 2, kh, 0x4E)   SC_DPP(1, 2, kh, 0x4E)
    SC_DPP(0, 3, kh, 0x1B)   SC_DPP(1, 3, kh, 0x1B)
    SC_DPP(0, 4, k7, 0x1B)   SC_DPP(1, 4, k7, 0x1B)
    SC_DPP(0, 5, k7, 0x4E)   SC_DPP(1, 5, k7, 0x4E)
    SC_DPP(0, 6, k7, 0xB1)   SC_DPP(1, 6, k7, 0xB1)
    SC_ID(0, 7, k7)          SC_ID(1, 7, k7)
#undef SC_ID
#undef SC_DPP

    // softmax, exp2 domain, no max-subtract (shift-invariant; |s| << 127);
    // normalized weights packed to h2 (both halves) for pk_fma combine.
    h2 eA[2][8], eB[2][8];
#pragma unroll
    for (int i = 0; i < 2; ++i) {
        float e0[8], e1[8];
        float sum0 = 0.f, sum1 = 0.f;
#pragma unroll
        for (int m = 0; m < 8; ++m) {
            e0[m] = exp2f(s0[i][m]); sum0 += e0[m];
            e1[m] = exp2f(s1[i][m]); sum1 += e1[m];
        }
        float r0 = __builtin_amdgcn_rcpf(sum0);
        float r1 = __builtin_amdgcn_rcpf(sum1);
#pragma unroll
        for (int m = 0; m < 8; ++m) {
            float n0 = e0[m] * r0, n1 = e1[m] * r1;
            eA[i][m] = __builtin_amdgcn_cvt_pkrtz(n0, n0);
            eB[i][m] = __builtin_amdgcn_cvt_pkrtz(n1, n1);
        }
    }

    h2 v7[2][8];
#pragma unroll
    for (int d = 0; d < 8; ++d) {
        v7[0][d] = DPPH2(vh[0][d], 0x141);
        v7[1][d] = DPPH2(vh[1][d], 0x141);
    }

    // ctx accumulated in packed fp16 (v_pk_fma_f16); cx[i][0..3]=head0 pairs,
    // cx[i][4..7]=head1 pairs -- directly the W3 input fragments.
    h2 cx[2][8];
    h2 hz; hz.x = (__fp16)0.f; hz.y = (__fp16)0.f;
#pragma unroll
    for (int i = 0; i < 2; ++i)
#pragma unroll
        for (int d = 0; d < 8; ++d) cx[i][d] = hz;
#define CTX_ID(i, slot, VS) { \
    _Pragma("unroll") for (int d = 0; d < 4; ++d) { \
        cx[i][d]     = PKFMA(eA[i][slot], VS[i][d],     cx[i][d]); \
        cx[i][4 + d] = PKFMA(eB[i][slot], VS[i][4 + d], cx[i][4 + d]); } }
#define CTX_DPP(i, slot, VS, CTRL) { \
    _Pragma("unroll") for (int d = 0; d < 4; ++d) { \
        cx[i][d]     = PKFMA(eA[i][slot], DPPH2(VS[i][d], CTRL),     cx[i][d]); \
        cx[i][4 + d] = PKFMA(eB[i][slot], DPPH2(VS[i][4 + d], CTRL), cx[i][4 + d]); } }
    CTX_ID(0, 0, vh)          CTX_ID(1, 0, vh)
    CTX_DPP(0, 1, vh, 0xB1)   CTX_DPP(1, 1, vh, 0xB1)
    CTX_DPP(0, 2, vh, 0x4E)   CTX_DPP(1, 2, vh, 0x4E)
    CTX_DPP(0, 3, vh, 0x1B)   CTX_DPP(1, 3, vh, 0x1B)
    CTX_DPP(0, 4, v7, 0x1B)   CTX_DPP(1, 4, v7, 0x1B)
    CTX_DPP(0, 5, v7, 0x4E)   CTX_DPP(1, 5, v7, 0x4E)
    CTX_DPP(0, 6, v7, 0xB1)   CTX_DPP(1, 6, v7, 0xB1)
    CTX_ID(0, 7, v7)          CTX_ID(1, 7, v7)
#undef CTX_ID
#undef CTX_DPP

    // fused out_proj+fc (16->32, relu) via fdot2; ctx already fp16 packed
    h2 yh[2][16];
#pragma unroll
    for (int i = 0; i < 16; ++i) {
        float ba = b3[2 * i], bb = b3[2 * i + 1];
        float ya0 = ba, yb0 = bb, ya1 = ba, yb1 = bb;
#pragma unroll
        for (int jj = 0; jj < 8; ++jj) {
            h2 wa = w3h[(2 * i) * 8 + jj];
            h2 wb = w3h[(2 * i + 1) * 8 + jj];
            ya0 = FDOT2(cx[0][jj], wa, ya0);
            ya1 = FDOT2(cx[1][jj], wa, ya1);
            yb0 = FDOT2(cx[0][jj], wb, yb0);
            yb1 = FDOT2(cx[1][jj], wb, yb1);
        }
        yh[0][i] = __builtin_amdgcn_cvt_pkrtz(fmaxf(ya0, 0.f), fmaxf(yb0, 0.f));
        yh[1][i] = __builtin_amdgcn_cvt_pkrtz(fmaxf(ya1, 0.f), fmaxf(yb1, 0.f));
    }

    // mean over 8 tokens: full ds_swizzle butterfly (xor1/xor2/xor4)
#pragma unroll
    for (int i = 0; i < 16; ++i) {
#pragma unroll
        for (int j = 0; j < 2; ++j) {
            yh[j][i] = yh[j][i] + SWZH(yh[j][i], 0x041F);
            yh[j][i] = yh[j][i] + SWZH(yh[j][i], 0x081F);
            yh[j][i] = yh[j][i] + SWZH(yh[j][i], 0x101F);
        }
    }

    // fco: weights loaded as 4 x dwordx4 per output row (L1-resident)
    const f32x4* fw4 = reinterpret_cast<const f32x4*>(fowh);
    float o4a[4], o4b[4];
#pragma unroll
    for (int j = 0; j < 4; ++j) {
        int oo = l * 4 + j;
        float acc0 = 0.f, acc1 = 0.f;
#pragma unroll
        for (int q = 0; q < 4; ++q) {
            f32x4 wv = fw4[oo * 4 + q];
            h2 w0 = f2h(wv.x), w1v = f2h(wv.y), w2v = f2h(wv.z), w3v = f2h(wv.w);
            acc0 = FDOT2(yh[0][q * 4 + 0], w0, acc0);
            acc1 = FDOT2(yh[1][q * 4 + 0], w0, acc1);
            acc0 = FDOT2(yh[0][q * 4 + 1], w1v, acc0);
            acc1 = FDOT2(yh[1][q * 4 + 1], w1v, acc1);
            acc0 = FDOT2(yh[0][q * 4 + 2], w2v, acc0);
            acc1 = FDOT2(yh[1][q * 4 + 2], w2v, acc1);
            acc0 = FDOT2(yh[0][q * 4 + 3], w3v, acc0);
            acc1 = FDOT2(yh[1][q * 4 + 3], w3v, acc1);
        }
        float bo = fob[oo];
        o4a[j] = fmaf(acc0, 0.125f, bo);
        o4b[j] = fmaf(acc1, 0.125f, bo);
    }
    f32x4 res0; res0.x = o4a[0]; res0.y = o4a[1]; res0.z = o4a[2]; res0.w = o4a[3];
    __builtin_nontemporal_store(res0, reinterpret_cast<f32x4*>(out) + (b0 * 8 + l));
    if (have1) {
        f32x4 res1; res1.x = o4b[0]; res1.y = o4b[1]; res1.z = o4b[2]; res1.w = o4b[3];
        __builtin_nontemporal_store(res1, reinterpret_cast<f32x4*>(out) + (b1 * 8 + l));
    }
}

// ---------------- fallback: monolithic kernel (if ws too small) ----------------
__global__ __launch_bounds__(256) void loop_embed_kernel(
    const float* __restrict__ nf, const int* __restrict__ s2l,
    const float* __restrict__ w1, const float* __restrict__ b1,
    const float* __restrict__ w2, const float* __restrict__ b2,
    const float* __restrict__ wip, const float* __restrict__ bip,
    const float* __restrict__ w3, const float* __restrict__ b3,
    const float* __restrict__ fow, const float* __restrict__ fob,
    float* __restrict__ out, int B)
{
    int tid = blockIdx.x * 256 + threadIdx.x;
    int b = tid >> 3;
    if (b >= B) return;
    int l = tid & 7;
    int idx = s2l[b * 8 + l];
    const float2* nfp = reinterpret_cast<const float2*>(nf);
    float2 p0 = nfp[idx * 3 + 0], p1 = nfp[idx * 3 + 1], p2 = nfp[idx * 3 + 2];
    float f[6] = {p0.x, p0.y, p1.x, p1.y, p2.x, p2.y};
    float h[32];
#pragma unroll
    for (int o = 0; o < 32; ++o) {
        float acc = b1[o];
#pragma unroll
        for (int i = 0; i < 6; ++i) acc = fmaf(f[i], w1[o * 6 + i], acc);
        h[o] = fmaxf(acc, 0.f);
    }
    float x[16];
#pragma unroll
    for (int e = 0; e < 16; ++e) {
        float acc = b2[e];
#pragma unroll
        for (int i = 0; i < 32; ++i) acc = fmaf(h[i], w2[e * 32 + i], acc);
        x[e] = acc;
    }
    float q[16], k[16], v[16];
#pragma unroll
    for (int c = 0; c < 16; ++c) {
        float aq = bip[c], ak = bip[16 + c], av = bip[32 + c];
#pragma unroll
        for (int e = 0; e < 16; ++e) {
            aq = fmaf(x[e], wip[c * 16 + e], aq);
            ak = fmaf(x[e], wip[(16 + c) * 16 + e], ak);
            av = fmaf(x[e], wip[(32 + c) * 16 + e], av);
        }
        q[c] = aq; k[c] = ak; v[c] = av;
    }
    int lane = threadIdx.x & 63;
    int gb = lane & 56;
    float s0[8], s1[8];
#pragma unroll
    for (int m = 0; m < 8; ++m) {
        float a0 = 0.f, a1 = 0.f;
#pragma unroll
        for (int d = 0; d < 8; ++d) {
            a0 = fmaf(q[d], __shfl(k[d], gb + m, 64), a0);
            a1 = fmaf(q[8 + d], __shfl(k[8 + d], gb + m, 64), a1);
        }
        s0[m] = a0; s1[m] = a1;
    }
    const float sc = 0.35355339059327373f;
    float mx0 = s0[0], mx1 = s1[0];
#pragma unroll
    for (int m = 1; m < 8; ++m) { mx0 = fmaxf(mx0, s0[m]); mx1 = fmaxf(mx1, s1[m]); }
    float e0[8], e1[8];
    float sum0 = 0.f, sum1 = 0.f;
#pragma unroll
    for (int m = 0; m < 8; ++m) {
        e0[m] = __expf((s0[m] - mx0) * sc); sum0 += e0[m];
        e1[m] = __expf((s1[m] - mx1) * sc); sum1 += e1[m];
    }
    float r0 = 1.0f / sum0, r1 = 1.0f / sum1;
    float ctx[16];
#pragma unroll
    for (int c = 0; c < 16; ++c) ctx[c] = 0.f;
#pragma unroll
    for (int m = 0; m < 8; ++m) {
#pragma unroll
        for (int c = 0; c < 8; ++c)
            ctx[c] = fmaf(e0[m], __shfl(v[c], gb + m, 64), ctx[c]);
#pragma unroll
        for (int c = 8; c < 16; ++c)
            ctx[c] = fmaf(e1[m], __shfl(v[c], gb + m, 64), ctx[c]);
    }
#pragma unroll
    for (int c = 0; c < 8; ++c)  ctx[c] *= r0;
#pragma unroll
    for (int c = 8; c < 16; ++c) ctx[c] *= r1;
    float y[32];
#pragma unroll
    for (int o = 0; o < 32; ++o) {
        float acc = b3[o];
#pragma unroll
        for (int j = 0; j < 16; ++j) acc = fmaf(ctx[j], w3[o * 16 + j], acc);
        y[o] = fmaxf(acc, 0.f);
    }
#pragma unroll
    for (int o = 0; o < 32; ++o) {
        y[o] += __shfl_xor(y[o], 1, 64);
        y[o] += __shfl_xor(y[o], 2, 64);
        y[o] += __shfl_xor(y[o], 4, 64);
    }
    float o4[4];
#pragma unroll
    for (int j = 0; j < 4; ++j) {
        int oo = l * 4 + j;
        float acc = 0.f;
#pragma unroll
        for (int i = 0; i < 32; ++i) acc = fmaf(y[i], fow[oo * 32 + i], acc);
        o4[j] = fmaf(acc, 0.125f, fob[oo]);
    }
    reinterpret_cast<float4*>(out)[b * 8 + l] = make_float4(o4[0], o4[1], o4[2], o4[3]);
}

extern "C" void kernel_launch(void* const* d_in, const int* in_sizes, int n_in,
                              void* d_out, int out_size, void* d_ws, size_t ws_size,
                              hipStream_t stream) {
    const float* nf  = (const float*)d_in[0];
    const int*   s2l = (const int*)d_in[1];
    const float* w1  = (const float*)d_in[2];
    const float* b1  = (const float*)d_in[3];
    const float* w2  = (const float*)d_in[4];
    const float* b2  = (const float*)d_in[5];
    const float* wip = (const float*)d_in[6];
    const float* bip = (const float*)d_in[7];
    const float* opw = (const float*)d_in[8];
    const float* opb = (const float*)d_in[9];
    const float* fcw = (const float*)d_in[10];
    const float* fcb = (const float*)d_in[11];
    const float* fow = (const float*)d_in[12];
    const float* fob = (const float*)d_in[13];
    float* out = (float*)d_out;

    int N = in_sizes[0] / 6;
    int B = in_sizes[1] / 8;

    // ws layout (dwords): [0,256) w3h  [256,768) fowh  [768,800) b3
    //                     [800,1312) w3f (fallback)  [1312,...) fp16 qkv table
    unsigned* wsd = (unsigned*)d_ws;
    h2*    w3h  = (h2*)(wsd);
    h2*    fowh = (h2*)(wsd + 256);
    float* b3   = (float*)(wsd + 768);
    float* w3f  = (float*)(wsd + 800);
    float* qkvt = (float*)(wsd + 1312);   // 16B-aligned (1312*4 = 5248)

    size_t need = (size_t)(1312 + (size_t)N * 12) * 4;   // 12 dwords = 96 B/node

    if (ws_size >= need) {
        int NB = (N + 255) / 256;
        prep_kernel<<<NB + 1, 256, 0, stream>>>(
            nf, w1, b1, w2, b2, wip, bip, fcw, fcb, opw, opb, fow,
            qkvt, w3h, fowh, b3, w3f, N);
        int npair = (B + 1) >> 1;
        int blocks = (npair * 8 + 255) / 256;
        attn_tail_kernel<<<blocks, 256, 0, stream>>>(
            s2l, qkvt, w3h, b3, fowh, fob, out, B);
    } else {
        prep_kernel<<<1, 256, 0, stream>>>(
            nf, w1, b1, w2, b2, wip, bip, fcw, fcb, opw, opb, fow,
            qkvt, w3h, fowh, b3, w3f, 0);
        int blocks = (B * 8 + 255) / 256;
        loop_embed_kernel<<<blocks, 256, 0, stream>>>(
            nf, s2l, w1, b1, w2, b2, wip, bip, w3f, b3, fow, fob, out, B);
    }
    (void)n_in; (void)out_size;
}